// Round 1
// baseline (259.206 us; speedup 1.0000x reference)
//
#include <hip/hip_runtime.h>

// LinearBin: out = x @ sign(W)^T + bias
// B=131072, IN=512, OUT=512, fp32 in/out.
// Strategy: bf16 MFMA GEMM, W pre-binarized to fragment-major bf16 in d_ws,
// x converted fp32->bf16 during reg-staged LDS staging (fused, single HBM pass).
// BM=128 x BN=512 (full width) so x is read exactly once. HBM floor ~81us.

#define BATCH   131072
#define IN_F    512
#define OUT_F   512
#define BM      128
#define BK      64          // staged K-tile (2 MFMA k-steps of 32)
#define NKT     (IN_F / 32) // 16 mfma k-steps
#define NTILES  (IN_F / BK) // 8 staged tiles

using f32x4   = __attribute__((ext_vector_type(4))) float;
using short8  = __attribute__((ext_vector_type(8))) short;
using ushort8 = __attribute__((ext_vector_type(8))) unsigned short;

__device__ __forceinline__ unsigned short f2bf(float f) {
    union { float f; unsigned int u; } c{f};
    unsigned int u = c.u;
    return (unsigned short)((u + 0x7FFFu + ((u >> 16) & 1u)) >> 16); // RTNE
}

// ---------------- prep: binarize W into fragment-major bf16 ----------------
// layout: wf[((kt*32 + nf)*64 + lane)*8 + j] = sign(W[nf*16 + (lane&15)][kt*32 + (lane>>4)*8 + j])
// kt in [0,16), nf in [0,32), lane in [0,64), j in [0,8). Total 512KB.
__global__ void prep_w(const float* __restrict__ W, unsigned short* __restrict__ wf) {
    int t = blockIdx.x * blockDim.x + threadIdx.x; // 32768 threads
    int lane = t & 63;
    int nf   = (t >> 6) & 31;
    int kt   = t >> 11;
    int n = nf * 16 + (lane & 15);
    int k = kt * 32 + ((lane >> 4) << 3);
    const float* src = W + n * IN_F + k;
    f32x4 w0 = *(const f32x4*)(src);
    f32x4 w1 = *(const f32x4*)(src + 4);
    ushort8 o;
#pragma unroll
    for (int j = 0; j < 4; ++j) {
        o[j]     = (w0[j] >= 0.0f) ? 0x3F80u : 0xBF80u; // +1.0 / -1.0 bf16
        o[j + 4] = (w1[j] >= 0.0f) ? 0x3F80u : 0xBF80u;
    }
    *(ushort8*)(wf + (size_t)t * 8) = o;
}

// ---------------- GEMM ----------------
__device__ __forceinline__ void stage_tile(char* ldsbase, int wbyte0, int wbyte1,
                                           const f32x4* ld) {
    ushort8 p0, p1;
#pragma unroll
    for (int i = 0; i < 8; ++i) {
        p0[i] = f2bf(ld[i >> 2][i & 3]);
        p1[i] = f2bf(ld[2 + (i >> 2)][i & 3]);
    }
    *(ushort8*)(ldsbase + wbyte0) = p0;
    *(ushort8*)(ldsbase + wbyte1) = p1;
}

__global__ __launch_bounds__(512, 2) void gemm_bin(
    const float* __restrict__ X, const unsigned short* __restrict__ WF,
    const float* __restrict__ bias, float* __restrict__ out) {

    __shared__ unsigned short lds_a[2][BM * BK]; // 2 x 16KB, XOR-swizzled rows

    const int tid  = threadIdx.x;
    const int lane = tid & 63;
    const int wave = tid >> 6;
    const int wm   = wave >> 2;  // 0..1 -> 64-row half
    const int wn   = wave & 3;   // 0..3 -> 128-col strip
    const int mrow0 = blockIdx.x * BM;

    // --- staging geometry: thread -> (row, 16-col chunk) of the 128x64 tile
    const int sr = tid >> 2;          // 0..127
    const int sc = (tid & 3) * 16;    // 0,16,32,48
    const float* xsrc = X + (size_t)(mrow0 + sr) * IN_F + sc;
    const int swz_w  = (sr & 7) << 4;
    const int wbyte0 = (sr * 128 + sc * 2) ^ swz_w;
    const int wbyte1 = (sr * 128 + sc * 2 + 16) ^ swz_w;

    // --- A-frag read geometry
    const int arow   = wm * 64 + (lane & 15);     // +fm*16 later
    const int akbyte = (lane >> 4) << 4;          // k-chunk byte offset
    const int swz_r  = (lane & 7) << 4;           // == (row&7)<<4 for all fm

    f32x4 acc[4][8];
#pragma unroll
    for (int fm = 0; fm < 4; ++fm)
#pragma unroll
        for (int fn = 0; fn < 8; ++fn)
            acc[fm][fn] = (f32x4){0.f, 0.f, 0.f, 0.f};

    // prologue: stage tile 0
    {
        f32x4 ld0[4];
#pragma unroll
        for (int i = 0; i < 4; ++i) ld0[i] = *(const f32x4*)(xsrc + i * 4);
        stage_tile((char*)lds_a, wbyte0, wbyte1, ld0);
    }
    __syncthreads();

    f32x4 nld[4];
#pragma unroll 2
    for (int t = 0; t < NTILES; ++t) {
        const int buf = t & 1;
        if (t < NTILES - 1) {
#pragma unroll
            for (int i = 0; i < 4; ++i)
                nld[i] = *(const f32x4*)(xsrc + (t + 1) * BK + i * 4);
        }
        const char* abase = (const char*)lds_a + buf * (BM * BK * 2);
#pragma unroll
        for (int half = 0; half < 2; ++half) {
            const int kt = t * 2 + half;
            short8 bfr[8], afr[4];
#pragma unroll
            for (int fn = 0; fn < 8; ++fn)
                bfr[fn] = *(const short8*)(WF + ((size_t)((kt * 32 + wn * 8 + fn) * 64 + lane)) * 8);
#pragma unroll
            for (int fm = 0; fm < 4; ++fm) {
                const int row  = arow + fm * 16;
                const int byte = (row * 128 + half * 64 + akbyte) ^ swz_r;
                afr[fm] = *(const short8*)(abase + byte);
            }
#pragma unroll
            for (int fm = 0; fm < 4; ++fm)
#pragma unroll
                for (int fn = 0; fn < 8; ++fn)
                    acc[fm][fn] = __builtin_amdgcn_mfma_f32_16x16x32_bf16(
                        afr[fm], bfr[fn], acc[fm][fn], 0, 0, 0);
        }
        if (t < NTILES - 1) {
            char* wb = (char*)lds_a + (buf ^ 1) * (BM * BK * 2);
            stage_tile(wb, wbyte0, wbyte1, nld);
        }
        __syncthreads();
    }

    // epilogue: C/D layout col = lane&15, row = (lane>>4)*4 + j
    float bv[8];
#pragma unroll
    for (int fn = 0; fn < 8; ++fn)
        bv[fn] = bias[wn * 128 + fn * 16 + (lane & 15)];
    const int lcol = lane & 15;
    const int lrow = (lane >> 4) << 2;
#pragma unroll
    for (int fm = 0; fm < 4; ++fm) {
#pragma unroll
        for (int j = 0; j < 4; ++j) {
            float* dst = out + (size_t)(mrow0 + wm * 64 + fm * 16 + lrow + j) * OUT_F
                             + wn * 128 + lcol;
#pragma unroll
            for (int fn = 0; fn < 8; ++fn)
                dst[fn * 16] = acc[fm][fn][j] + bv[fn];
        }
    }
}

extern "C" void kernel_launch(void* const* d_in, const int* in_sizes, int n_in,
                              void* d_out, int out_size, void* d_ws, size_t ws_size,
                              hipStream_t stream) {
    const float* X    = (const float*)d_in[0];
    const float* W    = (const float*)d_in[1];
    const float* bias = (const float*)d_in[2];
    float* out        = (float*)d_out;
    unsigned short* wf = (unsigned short*)d_ws; // 512KB fragment-major binarized W

    hipLaunchKernelGGL(prep_w, dim3(128), dim3(256), 0, stream, W, wf);
    hipLaunchKernelGGL(gemm_bin, dim3(BATCH / BM), dim3(512), 0, stream,
                       X, wf, bias, out);
}

// Round 3
// 163.270 us; speedup vs baseline: 1.5876x; 1.5876x over previous
//
#include <hip/hip_runtime.h>

// LinearBin: out = x @ sign(W)^T + bias   (B=131072, IN=OUT=512, fp32)
// bf16 MFMA GEMM. W pre-binarized to 16x16x32-fragment-major bf16 in d_ws.
// v2: occupancy-focused. Wave tile 64x32 (acc=32 regs), 2 blocks/CU,
//     XCD swizzle pairs both N-halves of an M-strip on one XCD (x L2 reuse),
//     contiguous staging loads, 2-deep x prefetch, LDS-transposed epilogue.
// v2b: rename ushort4 alias (collides with HIP built-in vector type).

#define BATCH   131072
#define IN_F    512
#define OUT_F   512
#define BM      64
#define BN      256
#define BK      64
#define NTILES  (IN_F / BK)   // 8

using f32x4   = __attribute__((ext_vector_type(4))) float;
using short8  = __attribute__((ext_vector_type(8))) short;
using usv4    = __attribute__((ext_vector_type(4))) unsigned short;
using usv8    = __attribute__((ext_vector_type(8))) unsigned short;

__device__ __forceinline__ unsigned short f2bf(float f) {
    union { float f; unsigned int u; } c{f};
    unsigned int u = c.u;
    return (unsigned short)((u + 0x7FFFu + ((u >> 16) & 1u)) >> 16); // RTNE
}

// ---------------- prep: binarize W into fragment-major bf16 (verified r1) ----
// wf[((kt*32 + nf)*64 + lane)*8 + j] = sign(W[nf*16 + (lane&15)][kt*32 + (lane>>4)*8 + j])
__global__ void prep_w(const float* __restrict__ W, unsigned short* __restrict__ wf) {
    int t = blockIdx.x * blockDim.x + threadIdx.x; // 32768 threads
    int lane = t & 63;
    int nf   = (t >> 6) & 31;
    int kt   = t >> 11;
    int n = nf * 16 + (lane & 15);
    int k = kt * 32 + ((lane >> 4) << 3);
    const float* src = W + n * IN_F + k;
    f32x4 w0 = *(const f32x4*)(src);
    f32x4 w1 = *(const f32x4*)(src + 4);
    usv8 o;
#pragma unroll
    for (int j = 0; j < 4; ++j) {
        o[j]     = (w0[j] >= 0.0f) ? 0x3F80u : 0xBF80u;
        o[j + 4] = (w1[j] >= 0.0f) ? 0x3F80u : 0xBF80u;
    }
    *(usv8*)(wf + (size_t)t * 8) = o;
}

// ---------------- GEMM ----------------
__global__ __launch_bounds__(512, 4) void gemm_bin(
    const float* __restrict__ X, const unsigned short* __restrict__ WF,
    const float* __restrict__ bias, float* __restrict__ out) {

    __shared__ unsigned short lds_a[2][BM * BK];  // 2 x 8KB, XOR-swizzled
    __shared__ float lds_o[8 * BM * 32];          // 64KB epilogue transpose

    const int tid  = threadIdx.x;
    const int lane = tid & 63;
    const int wv   = tid >> 6;            // 0..7 -> 32-col strip

    // bijective XCD swizzle: both N-halves of an M-strip land on one XCD
    const int b   = blockIdx.x;           // grid = 4096 (%8==0)
    const int swz = (b & 7) * 512 + (b >> 3);
    const int m0  = (swz >> 1) * BM;
    const int nh  = swz & 1;
    const int col0 = nh * BN + wv * 32;

    // staging: 16 lanes cover one row's 256B contiguously; rows srow, srow+32
    const int srow = tid >> 4;            // 0..31
    const int sg   = tid & 15;            // 16B granule in row
    const float* xs = X + (size_t)(m0 + srow) * IN_F + sg * 4;
    const int swz_w = (srow & 7) << 4;    // (srow+32)&7 == srow&7
    const int wb0 = (srow * 128 + sg * 8) ^ swz_w;
    const int wb1 = ((srow + 32) * 128 + sg * 8) ^ swz_w;

    // A-frag read geometry
    const int ar = lane & 15;
    const int ak = (lane >> 4) << 4;
    const int swz_r = (ar & 7) << 4;      // row&7 invariant under +16*fm

    f32x4 acc[4][2];
#pragma unroll
    for (int fm = 0; fm < 4; ++fm)
#pragma unroll
        for (int fn = 0; fn < 2; ++fn)
            acc[fm][fn] = (f32x4){0.f, 0.f, 0.f, 0.f};

    // prologue: stage tile 0 synchronously, issue tile-1 loads
    {
        f32x4 l0 = *(const f32x4*)(xs);
        f32x4 l1 = *(const f32x4*)(xs + 32 * IN_F);
        usv4 p0, p1;
#pragma unroll
        for (int i = 0; i < 4; ++i) { p0[i] = f2bf(l0[i]); p1[i] = f2bf(l1[i]); }
        *(usv4*)((char*)lds_a + wb0) = p0;
        *(usv4*)((char*)lds_a + wb1) = p1;
    }
    f32x4 na0 = *(const f32x4*)(xs + BK);
    f32x4 na1 = *(const f32x4*)(xs + 32 * IN_F + BK);
    f32x4 nb0, nb1;
    __syncthreads();

#pragma unroll
    for (int t = 0; t < NTILES; ++t) {
        const int buf = t & 1;
        // issue x loads 2 tiles ahead
        if (t < NTILES - 2) {
            nb0 = *(const f32x4*)(xs + (t + 2) * BK);
            nb1 = *(const f32x4*)(xs + 32 * IN_F + (t + 2) * BK);
        }
        // convert + write tile t+1 into buf^1 (read of buf^1 finished at t-1's barrier)
        if (t < NTILES - 1) {
            char* wbase = (char*)lds_a + (buf ^ 1) * (BM * BK * 2);
            usv4 p0, p1;
#pragma unroll
            for (int i = 0; i < 4; ++i) { p0[i] = f2bf(na0[i]); p1[i] = f2bf(na1[i]); }
            *(usv4*)(wbase + wb0) = p0;
            *(usv4*)(wbase + wb1) = p1;
        }
        // compute tile t
        const char* abase = (const char*)lds_a + buf * (BM * BK * 2);
#pragma unroll
        for (int h = 0; h < 2; ++h) {
            const int kt = t * 2 + h;
            short8 bfr[2], afr[4];
#pragma unroll
            for (int fn = 0; fn < 2; ++fn)
                bfr[fn] = *(const short8*)(WF +
                    ((size_t)((kt * 32 + nh * 16 + wv * 2 + fn) * 64 + lane)) * 8);
#pragma unroll
            for (int fm = 0; fm < 4; ++fm) {
                const int row  = fm * 16 + ar;
                const int byte = (row * 128 + h * 64 + ak) ^ swz_r;
                afr[fm] = *(const short8*)(abase + byte);
            }
#pragma unroll
            for (int fm = 0; fm < 4; ++fm)
#pragma unroll
                for (int fn = 0; fn < 2; ++fn)
                    acc[fm][fn] = __builtin_amdgcn_mfma_f32_16x16x32_bf16(
                        afr[fm], bfr[fn], acc[fm][fn], 0, 0, 0);
        }
        na0 = nb0; na1 = nb1;
        __syncthreads();
    }

    // ---------- epilogue: acc -> LDS (swizzled) -> coalesced f32x4 stores ----
    const int lcol = lane & 15;
    const int lrow = (lane >> 4) << 2;
    float bv[2];
#pragma unroll
    for (int fn = 0; fn < 2; ++fn) bv[fn] = bias[col0 + fn * 16 + lcol];

    char* lw = (char*)(lds_o + wv * (BM * 32));
#pragma unroll
    for (int fm = 0; fm < 4; ++fm)
#pragma unroll
        for (int fn = 0; fn < 2; ++fn)
#pragma unroll
            for (int j = 0; j < 4; ++j) {
                const int row  = fm * 16 + lrow + j;
                const int colw = fn * 16 + lcol;
                const int byte = (row * 128 + colw * 4) ^ ((row & 7) << 4);
                *(float*)(lw + byte) = acc[fm][fn][j] + bv[fn];
            }
    asm volatile("s_waitcnt lgkmcnt(0)" ::: "memory"); // wave-local write->read order
#pragma unroll
    for (int r = 0; r < 8; ++r) {
        const int row  = r * 8 + (lane >> 3);
        const int byte = (row * 128 + (lane & 7) * 16) ^ ((row & 7) << 4);
        f32x4 v = *(const f32x4*)(lw + byte);
        *(f32x4*)(out + (size_t)(m0 + row) * OUT_F + col0 + (lane & 7) * 4) = v;
    }
}

extern "C" void kernel_launch(void* const* d_in, const int* in_sizes, int n_in,
                              void* d_out, int out_size, void* d_ws, size_t ws_size,
                              hipStream_t stream) {
    const float* X    = (const float*)d_in[0];
    const float* W    = (const float*)d_in[1];
    const float* bias = (const float*)d_in[2];
    float* o          = (float*)d_out;
    unsigned short* wf = (unsigned short*)d_ws; // 512KB fragment-major binarized W

    hipLaunchKernelGGL(prep_w, dim3(128), dim3(256), 0, stream, W, wf);
    hipLaunchKernelGGL(gemm_bin, dim3((BATCH / BM) * (OUT_F / BN)), dim3(512), 0, stream,
                       X, wf, bias, o);
}